// Round 8
// baseline (250.104 us; speedup 1.0000x reference)
//
#include <hip/hip_runtime.h>
#include <hip/hip_bf16.h>

typedef __attribute__((ext_vector_type(8))) __bf16 bf16x8;
typedef __attribute__((ext_vector_type(4))) float f32x4;

#define F_DIM 512
#define D_DIM 128
#define RPB 128            // rows per bucket (bucket = row >> 7)
#define MAXBUK 1024
#define BIN_CHUNK 4096

__device__ __forceinline__ unsigned short f32_to_bf16_rn(float x) {
    union { float f; unsigned u; } v; v.f = x;
    unsigned u = v.u;
    unsigned rounded = u + 0x7fffu + ((u >> 16) & 1u);
    return (unsigned short)(rounded >> 16);
}
__device__ __forceinline__ float bf16_to_f32(unsigned short u) {
    return __uint_as_float((unsigned)u << 16);
}

__device__ __forceinline__ void gload_lds16(const void* g, void* l) {
    __builtin_amdgcn_global_load_lds(
        (const __attribute__((address_space(1))) void*)g,
        (__attribute__((address_space(3))) void*)l, 16, 0, 0);
}

__device__ __forceinline__ bf16x8 cvt8(float4 a, float4 b) {
    bf16x8 r;
    r[0] = (__bf16)a.x; r[1] = (__bf16)a.y; r[2] = (__bf16)a.z; r[3] = (__bf16)a.w;
    r[4] = (__bf16)b.x; r[5] = (__bf16)b.y; r[6] = (__bf16)b.z; r[7] = (__bf16)b.w;
    return r;
}

// fused: Wt transpose-convert (blocks 0..255) + cursor init (block 256)
__global__ void prep_kernel(const float* __restrict__ W, unsigned short* __restrict__ Wt,
                            int* __restrict__ cursor, int nbuk, int cap) {
    int b = blockIdx.x;
    if (b < 256) {
        int idx = b * 256 + threadIdx.x;   // 65536 total
        int n = idx >> 9;
        int k = idx & 511;
        Wt[idx] = f32_to_bf16_rn(W[k * D_DIM + n]);
    } else {
        for (int i = threadIdx.x; i < nbuk; i += 256) cursor[i] = i * cap;
    }
}

// support = relu(feature @ W) -> bf16. 128(M)x128(N), BK=32, 4 waves.
// A staged fp32 -> LDS via global_load_lds (16B), XOR-chunk-swizzled on the
// global-source side and on the LDS-read side (conflict-free, no padding).
// B fragments read directly from L1/L2-resident Wt (no LDS, no staging).
// One barrier per K-step; the 4 gload_lds issue at the top and land under
// the compute phase (drained by the barrier's vmcnt(0)).
__global__ __launch_bounds__(256) void gemm_relu_gll(
    const float* __restrict__ A,
    const unsigned short* __restrict__ Bt,
    unsigned short* __restrict__ Sb,
    int Nrows)
{
    __shared__ float Al[2 * 128 * 32];   // 32 KB: [buf][row][8 chunks of 16B]

    const int tid  = threadIdx.x;
    const int wave = tid >> 6;
    const int lane = tid & 63;
    const int g    = lane >> 4;
    const int r16  = lane & 15;
    const int m0   = blockIdx.x * 128;

    // staging map: i = it*256+tid; row=i>>3, chunk=i&7; source chunk = chunk^(row&7)
    const float* gsrc[4];
    int ldsoff[4];                        // wave-uniform byte offset
#pragma unroll
    for (int it = 0; it < 4; ++it) {
        int i    = it * 256 + tid;
        int row  = i >> 3;
        int csrc = (i & 7) ^ (row & 7);
        int arow = m0 + row;
        if (arow >= Nrows) arow = Nrows - 1;      // duplicate-safe; stores guarded
        gsrc[it]   = A + (size_t)arow * F_DIM + csrc * 4;
        ldsoff[it] = (it * 256 + wave * 64) * 16; // lane*16 added by HW
    }

    f32x4 acc[2][8];
#pragma unroll
    for (int i = 0; i < 2; ++i)
#pragma unroll
        for (int j = 0; j < 8; ++j) acc[i][j] = (f32x4)0.0f;

    // prologue: stage K-step 0 into buf 0
#pragma unroll
    for (int it = 0; it < 4; ++it)
        gload_lds16(gsrc[it], (char*)Al + ldsoff[it]);
    __syncthreads();

#pragma unroll
    for (int ks = 0; ks < 16; ++ks) {
        const int cur = ks & 1;
        if (ks < 15) {                    // issue next-tile DMA first
#pragma unroll
            for (int it = 0; it < 4; ++it)
                gload_lds16(gsrc[it] + (ks + 1) * 32,
                            (char*)Al + (cur ^ 1) * 16384 + ldsoff[it]);
        }

        // B fragments straight from Wt (8 KB step-slice, L1-resident)
        bf16x8 bfr[8];
#pragma unroll
        for (int nf = 0; nf < 8; ++nf)
            bfr[nf] = *(const bf16x8*)&Bt[(size_t)(nf * 16 + r16) * F_DIM + ks * 32 + g * 8];

        // A fragments from swizzled LDS, packed-convert to bf16
        const char* Ab = (const char*)Al + cur * 16384;
        bf16x8 af[2];
#pragma unroll
        for (int mf = 0; mf < 2; ++mf) {
            int row = wave * 32 + mf * 16 + r16;
            int sw  = row & 7;
            float4 lo = *(const float4*)(Ab + row * 128 + ((2 * g)     ^ sw) * 16);
            float4 hi = *(const float4*)(Ab + row * 128 + ((2 * g + 1) ^ sw) * 16);
            af[mf] = cvt8(lo, hi);
        }

#pragma unroll
        for (int nf = 0; nf < 8; ++nf) {
            acc[0][nf] = __builtin_amdgcn_mfma_f32_16x16x32_bf16(af[0], bfr[nf], acc[0][nf], 0, 0, 0);
            acc[1][nf] = __builtin_amdgcn_mfma_f32_16x16x32_bf16(af[1], bfr[nf], acc[1][nf], 0, 0, 0);
        }
        __syncthreads();                  // drains next-tile DMA + reuses buf
    }

#pragma unroll
    for (int mf = 0; mf < 2; ++mf) {
#pragma unroll
        for (int nf = 0; nf < 8; ++nf) {
#pragma unroll
            for (int r = 0; r < 4; ++r) {
                int row = m0 + wave * 32 + mf * 16 + g * 4 + r;
                if (row < Nrows) {
                    float v = acc[mf][nf][r];
                    Sb[(size_t)row * D_DIM + nf * 16 + r16] = f32_to_bf16_rn(v > 0.f ? v : 0.f);
                }
            }
        }
    }
}

// bin edges by destination bucket (row>>7). Per-block LDS histogram ->
// one global cursor atomic per (block,bucket) reserving a contiguous run ->
// edges written into their run (L2 merges the 8B writes within a run).
__global__ __launch_bounds__(256) void bin_kernel(
    const int* __restrict__ ei, const float* __restrict__ ev,
    int* __restrict__ cursor, uint2* __restrict__ ecv, int E, int nbuk)
{
    __shared__ int cnt[MAXBUK];
    __shared__ int bas[MAXBUK];
    const int tid = threadIdx.x;
    const int e0 = blockIdx.x * BIN_CHUNK;
    const int e1 = min(e0 + BIN_CHUNK, E);

    for (int i = tid; i < nbuk; i += 256) cnt[i] = 0;
    __syncthreads();
    for (int e = e0 + tid; e < e1; e += 256)
        atomicAdd(&cnt[ei[e] >> 7], 1);
    __syncthreads();
    for (int i = tid; i < nbuk; i += 256) {
        int c = cnt[i];
        bas[i] = c ? atomicAdd(&cursor[i], c) : 0;
        cnt[i] = 0;
    }
    __syncthreads();
    for (int e = e0 + tid; e < e1; e += 256) {
        int r = ei[e];
        int b = r >> 7;
        int slot = atomicAdd(&cnt[b], 1);
        uint2 cv;
        cv.x = ((unsigned)ei[E + e] << 7) | (unsigned)(r & 127);
        cv.y = __float_as_uint(ev[e]);
        ecv[(size_t)bas[b] + slot] = cv;
    }
}

// one block per bucket: counting-sort the bucket's edges by row (128-way),
// all traffic within a ~22 KB L2-hot region. Publishes rowoff/rowcnt.
__global__ __launch_bounds__(256) void bsort_kernel(
    const uint2* __restrict__ ecv, const int* __restrict__ cursor,
    uint2* __restrict__ ecv2, int* __restrict__ rowoff, int* __restrict__ rowcnt,
    int cap, int Nrows)
{
    __shared__ int cnt[RPB];
    __shared__ int base[RPB];
    const int tid = threadIdx.x;
    const int b   = blockIdx.x;
    const int beg = b * cap;
    const int end = cursor[b];

    if (tid < RPB) cnt[tid] = 0;
    __syncthreads();
    for (int i = beg + tid; i < end; i += 256)
        atomicAdd(&cnt[ecv[i].x & 127], 1);
    __syncthreads();
    if (tid < 64) {
        int carry = 0;
#pragma unroll
        for (int c = 0; c < 2; ++c) {
            int idx = c * 64 + tid;
            int v = cnt[idx];
            int orig = v;
            for (int d = 1; d < 64; d <<= 1) {
                int t = __shfl_up(v, d, 64);
                if (tid >= d) v += t;
            }
            base[idx] = carry + v - orig;
            carry += __shfl(v, 63, 64);
        }
    }
    __syncthreads();
    if (tid < RPB) {
        int r = b * RPB + tid;
        if (r < Nrows) {
            rowoff[r] = beg + base[tid];
            rowcnt[r] = cnt[tid];
        }
        cnt[tid] = 0;   // reuse as per-row cursor
    }
    __syncthreads();
    for (int i = beg + tid; i < end; i += 256) {
        uint2 cv = ecv[i];
        int rl = cv.x & 127;
        int slot = atomicAdd(&cnt[rl], 1);
        ecv2[(size_t)beg + base[rl] + slot] = cv;
    }
}

// one wave per row: acc = sum(val * Sb[col]) (bf16 gathers, 256B/edge);
// out = acc + Sb[row] + bias. Register accumulate, no atomics.
__global__ __launch_bounds__(256) void accum_kernel(
    const uint2* __restrict__ ecv2, const int* __restrict__ rowoff,
    const int* __restrict__ rowcnt, const unsigned short* __restrict__ Sb,
    const float* __restrict__ bias, float* __restrict__ out, int n)
{
    int wid = (blockIdx.x * 256 + threadIdx.x) >> 6;
    if (wid >= n) return;
    int lane = threadIdx.x & 63;
    int c2 = lane * 2;

    int start = rowoff[wid];
    int end   = start + rowcnt[wid];

    float ax = 0.f, ay = 0.f;
    int i = start;
    for (; i + 3 < end; i += 4) {
        uint2 cv0 = ecv2[i];
        uint2 cv1 = ecv2[i + 1];
        uint2 cv2 = ecv2[i + 2];
        uint2 cv3 = ecv2[i + 3];
        ushort2 s0 = *(const ushort2*)&Sb[(size_t)(cv0.x >> 7) * D_DIM + c2];
        ushort2 s1 = *(const ushort2*)&Sb[(size_t)(cv1.x >> 7) * D_DIM + c2];
        ushort2 s2 = *(const ushort2*)&Sb[(size_t)(cv2.x >> 7) * D_DIM + c2];
        ushort2 s3 = *(const ushort2*)&Sb[(size_t)(cv3.x >> 7) * D_DIM + c2];
        float v0 = __uint_as_float(cv0.y);
        float v1 = __uint_as_float(cv1.y);
        float v2 = __uint_as_float(cv2.y);
        float v3 = __uint_as_float(cv3.y);
        ax += v0 * bf16_to_f32(s0.x) + v1 * bf16_to_f32(s1.x)
            + v2 * bf16_to_f32(s2.x) + v3 * bf16_to_f32(s3.x);
        ay += v0 * bf16_to_f32(s0.y) + v1 * bf16_to_f32(s1.y)
            + v2 * bf16_to_f32(s2.y) + v3 * bf16_to_f32(s3.y);
    }
    for (; i < end; ++i) {
        uint2 cv = ecv2[i];
        ushort2 s = *(const ushort2*)&Sb[(size_t)(cv.x >> 7) * D_DIM + c2];
        float v = __uint_as_float(cv.y);
        ax += v * bf16_to_f32(s.x);
        ay += v * bf16_to_f32(s.y);
    }

    ushort2 so = *(const ushort2*)&Sb[(size_t)wid * D_DIM + c2];
    float2 b = *(const float2*)&bias[c2];
    float2 o;
    o.x = ax + bf16_to_f32(so.x) + b.x;
    o.y = ay + bf16_to_f32(so.y) + b.y;
    *(float2*)&out[(size_t)wid * D_DIM + c2] = o;
}

extern "C" void kernel_launch(void* const* d_in, const int* in_sizes, int n_in,
                              void* d_out, int out_size, void* d_ws, size_t ws_size,
                              hipStream_t stream) {
    const float* feature = (const float*)d_in[0];
    const float* W       = (const float*)d_in[1];
    const float* bias    = (const float*)d_in[2];
    const float* ev      = (const float*)d_in[3];
    const int*   ei      = (const int*)d_in[4];
    float* out = (float*)d_out;

    const int N = in_sizes[0] / F_DIM;   // 100000
    const int E = in_sizes[3];           // 1600000
    const int nbuk = (N + RPB - 1) / RPB;            // 782
    int cap = (E + nbuk - 1) / nbuk;
    cap = cap + cap / 4 + 256;                       // ~2813, >>12 sigma slack

    char* ws = (char*)d_ws;
    size_t cur = 0;
    auto alloc = [&](size_t bytes) -> void* {
        void* p = ws + cur;
        cur = (cur + bytes + 255) & ~(size_t)255;
        return p;
    };
    unsigned short* Sb     = (unsigned short*)alloc((size_t)N * D_DIM * 2);
    unsigned short* Wt     = (unsigned short*)alloc((size_t)D_DIM * F_DIM * 2);
    int*            cursor = (int*)alloc((size_t)nbuk * 4);
    int*            rowoff = (int*)alloc((size_t)N * 4);
    int*            rowcnt = (int*)alloc((size_t)N * 4);
    uint2*          ecv    = (uint2*)alloc(((size_t)nbuk * cap + BIN_CHUNK) * 8);
    uint2*          ecv2   = (uint2*)alloc(((size_t)nbuk * cap + BIN_CHUNK) * 8);
    (void)ws_size;

    prep_kernel<<<257, 256, 0, stream>>>(W, Wt, cursor, nbuk, cap);
    gemm_relu_gll<<<(N + 127) / 128, 256, 0, stream>>>(feature, Wt, Sb, N);
    bin_kernel<<<(E + BIN_CHUNK - 1) / BIN_CHUNK, 256, 0, stream>>>(ei, ev, cursor, ecv, E, nbuk);
    bsort_kernel<<<nbuk, 256, 0, stream>>>(ecv, cursor, ecv2, rowoff, rowcnt, cap, N);
    accum_kernel<<<(N + 3) / 4, 256, 0, stream>>>(ecv2, rowoff, rowcnt, Sb, bias, out, N);
}

// Round 9
// 244.342 us; speedup vs baseline: 1.0236x; 1.0236x over previous
//
#include <hip/hip_runtime.h>
#include <hip/hip_bf16.h>

typedef __attribute__((ext_vector_type(8))) __bf16 bf16x8;
typedef __attribute__((ext_vector_type(4))) float f32x4;

#define F_DIM 512
#define D_DIM 128
#define RPB 128            // rows per bucket (bucket = row >> 7)
#define MAXBUK 1024
#define BIN_CHUNK 8192

#define WAITV(n) asm volatile("s_waitcnt vmcnt(" n ")" ::: "memory")
#define WAITLGKM0 asm volatile("s_waitcnt lgkmcnt(0)" ::: "memory")
#define ORDER_FENCE asm volatile("" ::: "memory")

__device__ __forceinline__ unsigned short f32_to_bf16_rn(float x) {
    union { float f; unsigned u; } v; v.f = x;
    unsigned u = v.u;
    unsigned rounded = u + 0x7fffu + ((u >> 16) & 1u);
    return (unsigned short)(rounded >> 16);
}
__device__ __forceinline__ float bf16_to_f32(unsigned short u) {
    return __uint_as_float((unsigned)u << 16);
}

__device__ __forceinline__ void gload_lds16(const void* g, void* l) {
    __builtin_amdgcn_global_load_lds(
        (const __attribute__((address_space(1))) void*)g,
        (__attribute__((address_space(3))) void*)l, 16, 0, 0);
}

__device__ __forceinline__ bf16x8 cvt8(float4 a, float4 b) {
    bf16x8 r;
    r[0] = (__bf16)a.x; r[1] = (__bf16)a.y; r[2] = (__bf16)a.z; r[3] = (__bf16)a.w;
    r[4] = (__bf16)b.x; r[5] = (__bf16)b.y; r[6] = (__bf16)b.z; r[7] = (__bf16)b.w;
    return r;
}

// fused: Wt transpose-convert (blocks 0..255) + cursor init (block 256)
__global__ void prep_kernel(const float* __restrict__ W, unsigned short* __restrict__ Wt,
                            int* __restrict__ cursor, int nbuk, int cap) {
    int b = blockIdx.x;
    if (b < 256) {
        int idx = b * 256 + threadIdx.x;   // 65536 total
        int n = idx >> 9;
        int k = idx & 511;
        Wt[idx] = f32_to_bf16_rn(W[k * D_DIM + n]);
    } else {
        for (int i = threadIdx.x; i < nbuk; i += 256) cursor[i] = i * cap;
    }
}

// support = relu(feature @ W) -> bf16. 128(M)x128(N), BK=32, 4 waves.
// BARRIER-FREE per-wave async pipeline:
//  - each wave stages ITS OWN 32 A-rows (fp32, XOR-chunk-swizzled source)
//    into wave-private LDS via global_load_lds, 3 buffers deep;
//  - B fragments prefetched one K-step ahead into registers (so the
//    compiler's B-wait is a counted vmcnt, never vmcnt(0));
//  - A-tile readiness enforced by exact counted s_waitcnt vmcnt(N)
//    (in-order counting: N = loads issued after that tile's 4 gloads).
// No __syncthreads anywhere -> no vmcnt(0) drain -> 2.5-step-deep pipeline.
__global__ __launch_bounds__(256) void gemm_relu_async(
    const float* __restrict__ A,
    const unsigned short* __restrict__ Bt,
    unsigned short* __restrict__ Sb,
    int Nrows)
{
    __shared__ float Al[3 * 128 * 32];   // 48 KB: [buf][row][8 chunks of 16B]

    const int tid  = threadIdx.x;
    const int wave = tid >> 6;
    const int lane = tid & 63;
    const int g    = lane >> 4;
    const int r16  = lane & 15;
    const int m0   = blockIdx.x * 128;

    // per-wave staging: instr it covers rows wave*32 + it*8 .. +7.
    // lane l -> local row it*8 + (l>>3), LDS chunk l&7, global chunk (l&7)^(l>>3).
    const float* gsrc[4];
    int wbase[4];                          // wave-uniform LDS byte base (HW adds lane*16)
#pragma unroll
    for (int it = 0; it < 4; ++it) {
        int row  = wave * 32 + it * 8 + (lane >> 3);
        int csrc = (lane & 7) ^ (lane >> 3);
        int arow = m0 + row;
        if (arow >= Nrows) arow = Nrows - 1;      // duplicate-safe; stores guarded
        gsrc[it]  = A + (size_t)arow * F_DIM + csrc * 4;
        wbase[it] = wave * 4096 + it * 1024;
    }

    auto stageA = [&](int ks, int buf) {
#pragma unroll
        for (int it = 0; it < 4; ++it)
            gload_lds16(gsrc[it] + ks * 32, (char*)Al + buf * 16384 + wbase[it]);
    };

    const unsigned short* bbase = Bt + (size_t)r16 * F_DIM + g * 8;
    bf16x8 bcur[8], bnext[8];
    auto loadB = [&](bf16x8* dst, int ks) {
#pragma unroll
        for (int nf = 0; nf < 8; ++nf)
            dst[nf] = *(const bf16x8*)(bbase + (size_t)nf * 16 * F_DIM + ks * 32);
    };

    f32x4 acc[2][8];
#pragma unroll
    for (int i = 0; i < 2; ++i)
#pragma unroll
        for (int j = 0; j < 8; ++j) acc[i][j] = (f32x4)0.0f;

    // prologue (order-pinned): A(0), B(0), A(1)
    stageA(0, 0);
    ORDER_FENCE;
    loadB(bcur, 0);
    ORDER_FENCE;
    stageA(1, 1);
    ORDER_FENCE;

#pragma unroll
    for (int ks = 0; ks < 16; ++ks) {
        if (ks < 15) loadB(bnext, ks + 1);
        if (ks < 14) {
            WAITLGKM0;                      // (ks+2)%3-buffer's old ds_reads retired
            stageA(ks + 2, (ks + 2) % 3);
        }
        // A(ks) readiness: loads issued after its 4 gloads (in-order vmcnt):
        //   steady (ks<=13): iters ks-1,ks: 2*(8 B + 4 A) = 24
        //   ks==14: 12 (iter 13) + 8 (B15) = 20;  ks==15: 8 (B15) = 8
        if (ks <= 13)      { WAITV("24"); }
        else if (ks == 14) { WAITV("20"); }
        else               { WAITV("8");  }
        __builtin_amdgcn_sched_barrier(0);

        const char* Ab = (const char*)Al + (ks % 3) * 16384;
        bf16x8 af[2];
#pragma unroll
        for (int mf = 0; mf < 2; ++mf) {
            int row = wave * 32 + mf * 16 + r16;
            int sw  = r16 & 7;
            float4 lo = *(const float4*)(Ab + row * 128 + ((2 * g) ^ sw) * 16);
            float4 hi = *(const float4*)(Ab + row * 128 + (((2 * g) | 1) ^ sw) * 16);
            af[mf] = cvt8(lo, hi);
        }

#pragma unroll
        for (int nf = 0; nf < 8; ++nf) {
            acc[0][nf] = __builtin_amdgcn_mfma_f32_16x16x32_bf16(af[0], bcur[nf], acc[0][nf], 0, 0, 0);
            acc[1][nf] = __builtin_amdgcn_mfma_f32_16x16x32_bf16(af[1], bcur[nf], acc[1][nf], 0, 0, 0);
        }

        if (ks < 15) {
#pragma unroll
            for (int nf = 0; nf < 8; ++nf) bcur[nf] = bnext[nf];
        }
    }

    // epilogue: relu + bf16 store
#pragma unroll
    for (int mf = 0; mf < 2; ++mf) {
#pragma unroll
        for (int nf = 0; nf < 8; ++nf) {
#pragma unroll
            for (int r = 0; r < 4; ++r) {
                int row = m0 + wave * 32 + mf * 16 + g * 4 + r;
                if (row < Nrows) {
                    float v = acc[mf][nf][r];
                    Sb[(size_t)row * D_DIM + nf * 16 + r16] = f32_to_bf16_rn(v > 0.f ? v : 0.f);
                }
            }
        }
    }
}

// bin edges by destination bucket (row>>7). Per-block LDS histogram ->
// one global cursor atomic per (block,bucket) reserving a contiguous run ->
// edges written into their run (L2 merges the 8B writes within a run).
__global__ __launch_bounds__(256) void bin_kernel(
    const int* __restrict__ ei, const float* __restrict__ ev,
    int* __restrict__ cursor, uint2* __restrict__ ecv, int E, int nbuk)
{
    __shared__ int cnt[MAXBUK];
    __shared__ int bas[MAXBUK];
    const int tid = threadIdx.x;
    const int e0 = blockIdx.x * BIN_CHUNK;
    const int e1 = min(e0 + BIN_CHUNK, E);

    for (int i = tid; i < nbuk; i += 256) cnt[i] = 0;
    __syncthreads();
    for (int e = e0 + tid; e < e1; e += 256)
        atomicAdd(&cnt[ei[e] >> 7], 1);
    __syncthreads();
    for (int i = tid; i < nbuk; i += 256) {
        int c = cnt[i];
        bas[i] = c ? atomicAdd(&cursor[i], c) : 0;
        cnt[i] = 0;
    }
    __syncthreads();
    for (int e = e0 + tid; e < e1; e += 256) {
        int r = ei[e];
        int b = r >> 7;
        int slot = atomicAdd(&cnt[b], 1);
        uint2 cv;
        cv.x = ((unsigned)ei[E + e] << 7) | (unsigned)(r & 127);
        cv.y = __float_as_uint(ev[e]);
        ecv[(size_t)bas[b] + slot] = cv;
    }
}

// one block per bucket: counting-sort the bucket's edges by row (128-way),
// all traffic within a ~22 KB L2-hot region. Publishes rowoff/rowcnt.
__global__ __launch_bounds__(256) void bsort_kernel(
    const uint2* __restrict__ ecv, const int* __restrict__ cursor,
    uint2* __restrict__ ecv2, int* __restrict__ rowoff, int* __restrict__ rowcnt,
    int cap, int Nrows)
{
    __shared__ int cnt[RPB];
    __shared__ int base[RPB];
    const int tid = threadIdx.x;
    const int b   = blockIdx.x;
    const int beg = b * cap;
    const int end = cursor[b];

    if (tid < RPB) cnt[tid] = 0;
    __syncthreads();
    for (int i = beg + tid; i < end; i += 256)
        atomicAdd(&cnt[ecv[i].x & 127], 1);
    __syncthreads();
    if (tid < 64) {
        int carry = 0;
#pragma unroll
        for (int c = 0; c < 2; ++c) {
            int idx = c * 64 + tid;
            int v = cnt[idx];
            int orig = v;
            for (int d = 1; d < 64; d <<= 1) {
                int t = __shfl_up(v, d, 64);
                if (tid >= d) v += t;
            }
            base[idx] = carry + v - orig;
            carry += __shfl(v, 63, 64);
        }
    }
    __syncthreads();
    if (tid < RPB) {
        int r = b * RPB + tid;
        if (r < Nrows) {
            rowoff[r] = beg + base[tid];
            rowcnt[r] = cnt[tid];
        }
        cnt[tid] = 0;   // reuse as per-row cursor
    }
    __syncthreads();
    for (int i = beg + tid; i < end; i += 256) {
        uint2 cv = ecv[i];
        int rl = cv.x & 127;
        int slot = atomicAdd(&cnt[rl], 1);
        ecv2[(size_t)beg + base[rl] + slot] = cv;
    }
}

// one wave per row: acc = sum(val * Sb[col]) (bf16 gathers, 256B/edge);
// out = acc + Sb[row] + bias. Register accumulate, no atomics.
__global__ __launch_bounds__(256) void accum_kernel(
    const uint2* __restrict__ ecv2, const int* __restrict__ rowoff,
    const int* __restrict__ rowcnt, const unsigned short* __restrict__ Sb,
    const float* __restrict__ bias, float* __restrict__ out, int n)
{
    int wid = (blockIdx.x * 256 + threadIdx.x) >> 6;
    if (wid >= n) return;
    int lane = threadIdx.x & 63;
    int c2 = lane * 2;

    int start = rowoff[wid];
    int end   = start + rowcnt[wid];

    float ax = 0.f, ay = 0.f;
    int i = start;
    for (; i + 3 < end; i += 4) {
        uint2 cv0 = ecv2[i];
        uint2 cv1 = ecv2[i + 1];
        uint2 cv2 = ecv2[i + 2];
        uint2 cv3 = ecv2[i + 3];
        ushort2 s0 = *(const ushort2*)&Sb[(size_t)(cv0.x >> 7) * D_DIM + c2];
        ushort2 s1 = *(const ushort2*)&Sb[(size_t)(cv1.x >> 7) * D_DIM + c2];
        ushort2 s2 = *(const ushort2*)&Sb[(size_t)(cv2.x >> 7) * D_DIM + c2];
        ushort2 s3 = *(const ushort2*)&Sb[(size_t)(cv3.x >> 7) * D_DIM + c2];
        float v0 = __uint_as_float(cv0.y);
        float v1 = __uint_as_float(cv1.y);
        float v2 = __uint_as_float(cv2.y);
        float v3 = __uint_as_float(cv3.y);
        ax += v0 * bf16_to_f32(s0.x) + v1 * bf16_to_f32(s1.x)
            + v2 * bf16_to_f32(s2.x) + v3 * bf16_to_f32(s3.x);
        ay += v0 * bf16_to_f32(s0.y) + v1 * bf16_to_f32(s1.y)
            + v2 * bf16_to_f32(s2.y) + v3 * bf16_to_f32(s3.y);
    }
    for (; i < end; ++i) {
        uint2 cv = ecv2[i];
        ushort2 s = *(const ushort2*)&Sb[(size_t)(cv.x >> 7) * D_DIM + c2];
        float v = __uint_as_float(cv.y);
        ax += v * bf16_to_f32(s.x);
        ay += v * bf16_to_f32(s.y);
    }

    ushort2 so = *(const ushort2*)&Sb[(size_t)wid * D_DIM + c2];
    float2 b = *(const float2*)&bias[c2];
    float2 o;
    o.x = ax + bf16_to_f32(so.x) + b.x;
    o.y = ay + bf16_to_f32(so.y) + b.y;
    *(float2*)&out[(size_t)wid * D_DIM + c2] = o;
}

extern "C" void kernel_launch(void* const* d_in, const int* in_sizes, int n_in,
                              void* d_out, int out_size, void* d_ws, size_t ws_size,
                              hipStream_t stream) {
    const float* feature = (const float*)d_in[0];
    const float* W       = (const float*)d_in[1];
    const float* bias    = (const float*)d_in[2];
    const float* ev      = (const float*)d_in[3];
    const int*   ei      = (const int*)d_in[4];
    float* out = (float*)d_out;

    const int N = in_sizes[0] / F_DIM;   // 100000
    const int E = in_sizes[3];           // 1600000
    const int nbuk = (N + RPB - 1) / RPB;            // 782
    int cap = (E + nbuk - 1) / nbuk;
    cap = cap + cap / 4 + 256;                       // ~2813, >>12 sigma slack

    char* ws = (char*)d_ws;
    size_t cur = 0;
    auto alloc = [&](size_t bytes) -> void* {
        void* p = ws + cur;
        cur = (cur + bytes + 255) & ~(size_t)255;
        return p;
    };
    unsigned short* Sb     = (unsigned short*)alloc((size_t)N * D_DIM * 2);
    unsigned short* Wt     = (unsigned short*)alloc((size_t)D_DIM * F_DIM * 2);
    int*            cursor = (int*)alloc((size_t)nbuk * 4);
    int*            rowoff = (int*)alloc((size_t)N * 4);
    int*            rowcnt = (int*)alloc((size_t)N * 4);
    uint2*          ecv    = (uint2*)alloc(((size_t)nbuk * cap + BIN_CHUNK) * 8);
    uint2*          ecv2   = (uint2*)alloc(((size_t)nbuk * cap + BIN_CHUNK) * 8);
    (void)ws_size;

    prep_kernel<<<257, 256, 0, stream>>>(W, Wt, cursor, nbuk, cap);
    gemm_relu_async<<<(N + 127) / 128, 256, 0, stream>>>(feature, Wt, Sb, N);
    bin_kernel<<<(E + BIN_CHUNK - 1) / BIN_CHUNK, 256, 0, stream>>>(ei, ev, cursor, ecv, E, nbuk);
    bsort_kernel<<<nbuk, 256, 0, stream>>>(ecv, cursor, ecv2, rowoff, rowcnt, cap, N);
    accum_kernel<<<(N + 3) / 4, 256, 0, stream>>>(ecv2, rowoff, rowcnt, Sb, bias, out, N);
}

// Round 10
// 224.738 us; speedup vs baseline: 1.1129x; 1.0872x over previous
//
#include <hip/hip_runtime.h>
#include <hip/hip_bf16.h>

typedef __attribute__((ext_vector_type(8))) __bf16 bf16x8;
typedef __attribute__((ext_vector_type(4))) float f32x4;

#define F_DIM 512
#define D_DIM 128
#define RPB 128            // rows per bucket (bucket = row >> 7)
#define MAXBUK 1024
#define BIN_CHUNK 8192
#define CAPMAX 3072        // >= runtime cap (2813); LDS sizing

__device__ __forceinline__ unsigned short f32_to_bf16_rn(float x) {
    union { float f; unsigned u; } v; v.f = x;
    unsigned u = v.u;
    unsigned rounded = u + 0x7fffu + ((u >> 16) & 1u);
    return (unsigned short)(rounded >> 16);
}
__device__ __forceinline__ float bf16_to_f32(unsigned short u) {
    return __uint_as_float((unsigned)u << 16);
}

// fused: Wt transpose-convert (blocks 0..255) + cursor init (block 256)
__global__ void prep_kernel(const float* __restrict__ W, unsigned short* __restrict__ Wt,
                            int* __restrict__ cursor, int nbuk, int cap) {
    int b = blockIdx.x;
    if (b < 256) {
        int idx = b * 256 + threadIdx.x;   // 65536 total
        int n = idx >> 9;
        int k = idx & 511;
        Wt[idx] = f32_to_bf16_rn(W[k * D_DIM + n]);
    } else {
        for (int i = threadIdx.x; i < nbuk; i += 256) cursor[i] = i * cap;
    }
}

// support = relu(feature @ W) -> bf16. 64(M)x128(N) tile, BK=32, 4 waves,
// reg-staged + LDS double-buffer, one barrier per K-step. (Best-measured
// structure: R7. R8/R9 async variants regressed.)
__global__ __launch_bounds__(256) void gemm_relu_pipe(
    const float* __restrict__ A,
    const unsigned short* __restrict__ Bt,
    unsigned short* __restrict__ Sb,
    int Nrows)
{
    __shared__ unsigned short Al[2 * 64 * 40];    // 10 KB
    __shared__ unsigned short Bl[2 * 128 * 40];   // 20 KB

    const int tid  = threadIdx.x;
    const int wave = tid >> 6;
    const int lane = tid & 63;
    const int g    = lane >> 4;
    const int r16  = lane & 15;
    const int m0   = blockIdx.x * 64;

    const int sar = tid >> 2;
    const int skq = tid & 3;
    int arow = m0 + sar;
    if (arow >= Nrows) arow = Nrows - 1;
    const float* aptr = A + (size_t)arow * F_DIM + skq * 8;
    const int awoff = sar * 40 + skq * 8;

    const int sbr = tid >> 1;
    const int skh = tid & 1;
    const unsigned short* bptr = Bt + (size_t)sbr * F_DIM + skh * 16;
    const int bwoff = sbr * 40 + skh * 16;

    float4 ar0, ar1;
    uint4  br0, br1;

    auto loadAB = [&](int ks) {
        const float4* pa = (const float4*)(aptr + ks * 32);
        ar0 = pa[0]; ar1 = pa[1];
        const uint4* pb = (const uint4*)(bptr + ks * 32);
        br0 = pb[0]; br1 = pb[1];
    };
    auto storeAB = [&](int buf) {
        union { uint4 q; __bf16 h[8]; } u;
        u.h[0]=(__bf16)ar0.x; u.h[1]=(__bf16)ar0.y; u.h[2]=(__bf16)ar0.z; u.h[3]=(__bf16)ar0.w;
        u.h[4]=(__bf16)ar1.x; u.h[5]=(__bf16)ar1.y; u.h[6]=(__bf16)ar1.z; u.h[7]=(__bf16)ar1.w;
        *(uint4*)&Al[buf * 2560 + awoff] = u.q;
        unsigned short* bw = &Bl[buf * 5120 + bwoff];
        *(uint4*)bw       = br0;
        *(uint4*)(bw + 8) = br1;
    };

    f32x4 acc[8];
#pragma unroll
    for (int j = 0; j < 8; ++j) acc[j] = (f32x4)0.0f;

    loadAB(0);
    storeAB(0);
    __syncthreads();

#pragma unroll
    for (int ks = 0; ks < 16; ++ks) {
        const int cur = ks & 1;
        if (ks < 15) loadAB(ks + 1);

        const unsigned short* Ab = Al + cur * 2560;
        const unsigned short* Bb = Bl + cur * 5120;
        bf16x8 af = *(const bf16x8*)&Ab[(wave * 16 + r16) * 40 + g * 8];
#pragma unroll
        for (int nf = 0; nf < 8; ++nf) {
            bf16x8 bf = *(const bf16x8*)&Bb[(nf * 16 + r16) * 40 + g * 8];
            acc[nf] = __builtin_amdgcn_mfma_f32_16x16x32_bf16(af, bf, acc[nf], 0, 0, 0);
        }

        if (ks < 15) storeAB(cur ^ 1);
        __syncthreads();
    }

#pragma unroll
    for (int nf = 0; nf < 8; ++nf) {
#pragma unroll
        for (int r = 0; r < 4; ++r) {
            int row = m0 + wave * 16 + g * 4 + r;
            if (row < Nrows) {
                float v = acc[nf][r];
                Sb[(size_t)row * D_DIM + nf * 16 + r16] = f32_to_bf16_rn(v > 0.f ? v : 0.f);
            }
        }
    }
}

// bin edges by destination bucket (row>>7). Per-block LDS histogram ->
// one global cursor atomic per (block,bucket) reserving a contiguous run ->
// edges written into their run (L2 merges the 8B writes within a run).
__global__ __launch_bounds__(256) void bin_kernel(
    const int* __restrict__ ei, const float* __restrict__ ev,
    int* __restrict__ cursor, uint2* __restrict__ ecv, int E, int nbuk)
{
    __shared__ int cnt[MAXBUK];
    __shared__ int bas[MAXBUK];
    const int tid = threadIdx.x;
    const int e0 = blockIdx.x * BIN_CHUNK;
    const int e1 = min(e0 + BIN_CHUNK, E);

    for (int i = tid; i < nbuk; i += 256) cnt[i] = 0;
    __syncthreads();
    for (int e = e0 + tid; e < e1; e += 256)
        atomicAdd(&cnt[ei[e] >> 7], 1);
    __syncthreads();
    for (int i = tid; i < nbuk; i += 256) {
        int c = cnt[i];
        bas[i] = c ? atomicAdd(&cursor[i], c) : 0;
        cnt[i] = 0;
    }
    __syncthreads();
    for (int e = e0 + tid; e < e1; e += 256) {
        int r = ei[e];
        int b = r >> 7;
        int slot = atomicAdd(&cnt[b], 1);
        uint2 cv;
        cv.x = ((unsigned)ei[E + e] << 7) | (unsigned)(r & 127);
        cv.y = __float_as_uint(ev[e]);
        ecv[(size_t)bas[b] + slot] = cv;
    }
}

// FUSED sort+accumulate: one block per bucket, 512 threads, 8 waves.
// Stage bucket edges into LDS, LDS counting-sort by local row, then each
// wave owns 16 rows: broadcast-read the row's edges from LDS, gather
// Sb[col] (bf16, 256B), register-accumulate; fused identity+bias epilogue.
// No ecv2/rowoff/rowcnt globals, no second edge round-trip.
__global__ __launch_bounds__(512) void sortaccum_kernel(
    const uint2* __restrict__ ecv, const int* __restrict__ cursor,
    const unsigned short* __restrict__ Sb, const float* __restrict__ bias,
    float* __restrict__ out, int Nrows, int cap)
{
    __shared__ uint2 raw[CAPMAX];   // 24 KB
    __shared__ uint2 srt[CAPMAX];   // 24 KB
    __shared__ int cnt[RPB];
    __shared__ int base[RPB];
    __shared__ int scur[RPB];

    const int tid = threadIdx.x;
    const int b   = blockIdx.x;
    const int beg = b * cap;
    const int n   = cursor[b] - beg;      // <= cap <= CAPMAX

    if (tid < RPB) cnt[tid] = 0;
    __syncthreads();
    for (int i = tid; i < n; i += 512) {
        uint2 cv = ecv[beg + i];
        raw[i] = cv;
        atomicAdd(&cnt[cv.x & 127], 1);
    }
    __syncthreads();
    // exclusive scan of 128 counts by wave 0 (two 64-chunks + carry)
    if (tid < 64) {
        int carry = 0;
#pragma unroll
        for (int c = 0; c < 2; ++c) {
            int idx = c * 64 + tid;
            int v = cnt[idx];
            int orig = v;
            for (int d = 1; d < 64; d <<= 1) {
                int t = __shfl_up(v, d, 64);
                if (tid >= d) v += t;
            }
            int excl = carry + v - orig;
            base[idx] = excl;
            scur[idx] = excl;
            carry += __shfl(v, 63, 64);
        }
    }
    __syncthreads();
    for (int i = tid; i < n; i += 512) {
        uint2 cv = raw[i];
        int slot = atomicAdd(&scur[cv.x & 127], 1);
        srt[slot] = cv;
    }
    __syncthreads();

    const int wv   = tid >> 6;
    const int lane = tid & 63;
    const int c2   = lane * 2;
    const int r0g  = b * RPB;

    for (int rr = 0; rr < 16; ++rr) {
        int rl  = wv * 16 + rr;
        int row = r0g + rl;
        if (row >= Nrows) break;
        int s = base[rl];
        int e = s + cnt[rl];

        float ax = 0.f, ay = 0.f;
        int i = s;
        for (; i + 3 < e; i += 4) {
            uint2 cv0 = srt[i];
            uint2 cv1 = srt[i + 1];
            uint2 cv2 = srt[i + 2];
            uint2 cv3 = srt[i + 3];
            ushort2 s0 = *(const ushort2*)&Sb[(size_t)(cv0.x >> 7) * D_DIM + c2];
            ushort2 s1 = *(const ushort2*)&Sb[(size_t)(cv1.x >> 7) * D_DIM + c2];
            ushort2 s2 = *(const ushort2*)&Sb[(size_t)(cv2.x >> 7) * D_DIM + c2];
            ushort2 s3 = *(const ushort2*)&Sb[(size_t)(cv3.x >> 7) * D_DIM + c2];
            float v0 = __uint_as_float(cv0.y);
            float v1 = __uint_as_float(cv1.y);
            float v2 = __uint_as_float(cv2.y);
            float v3 = __uint_as_float(cv3.y);
            ax += v0 * bf16_to_f32(s0.x) + v1 * bf16_to_f32(s1.x)
                + v2 * bf16_to_f32(s2.x) + v3 * bf16_to_f32(s3.x);
            ay += v0 * bf16_to_f32(s0.y) + v1 * bf16_to_f32(s1.y)
                + v2 * bf16_to_f32(s2.y) + v3 * bf16_to_f32(s3.y);
        }
        for (; i < e; ++i) {
            uint2 cv = srt[i];
            ushort2 sv = *(const ushort2*)&Sb[(size_t)(cv.x >> 7) * D_DIM + c2];
            float v = __uint_as_float(cv.y);
            ax += v * bf16_to_f32(sv.x);
            ay += v * bf16_to_f32(sv.y);
        }

        ushort2 so = *(const ushort2*)&Sb[(size_t)row * D_DIM + c2];
        float2 bv = *(const float2*)&bias[c2];
        float2 o;
        o.x = ax + bf16_to_f32(so.x) + bv.x;
        o.y = ay + bf16_to_f32(so.y) + bv.y;
        *(float2*)&out[(size_t)row * D_DIM + c2] = o;
    }
}

extern "C" void kernel_launch(void* const* d_in, const int* in_sizes, int n_in,
                              void* d_out, int out_size, void* d_ws, size_t ws_size,
                              hipStream_t stream) {
    const float* feature = (const float*)d_in[0];
    const float* W       = (const float*)d_in[1];
    const float* bias    = (const float*)d_in[2];
    const float* ev      = (const float*)d_in[3];
    const int*   ei      = (const int*)d_in[4];
    float* out = (float*)d_out;

    const int N = in_sizes[0] / F_DIM;   // 100000
    const int E = in_sizes[3];           // 1600000
    const int nbuk = (N + RPB - 1) / RPB;            // 782
    int cap = (E + nbuk - 1) / nbuk;
    cap = cap + cap / 4 + 256;                       // ~2813 (<= CAPMAX)
    if (cap > CAPMAX) cap = CAPMAX;

    char* ws = (char*)d_ws;
    size_t cur = 0;
    auto alloc = [&](size_t bytes) -> void* {
        void* p = ws + cur;
        cur = (cur + bytes + 255) & ~(size_t)255;
        return p;
    };
    unsigned short* Sb     = (unsigned short*)alloc((size_t)N * D_DIM * 2);
    unsigned short* Wt     = (unsigned short*)alloc((size_t)D_DIM * F_DIM * 2);
    int*            cursor = (int*)alloc((size_t)nbuk * 4);
    uint2*          ecv    = (uint2*)alloc(((size_t)nbuk * cap + BIN_CHUNK) * 8);
    (void)ws_size;

    prep_kernel<<<257, 256, 0, stream>>>(W, Wt, cursor, nbuk, cap);
    gemm_relu_pipe<<<(N + 63) / 64, 256, 0, stream>>>(feature, Wt, Sb, N);
    bin_kernel<<<(E + BIN_CHUNK - 1) / BIN_CHUNK, 256, 0, stream>>>(ei, ev, cursor, ecv, E, nbuk);
    sortaccum_kernel<<<nbuk, 512, 0, stream>>>(ecv, cursor, Sb, bias, out, N, cap);
}

// Round 11
// 198.980 us; speedup vs baseline: 1.2569x; 1.1295x over previous
//
#include <hip/hip_runtime.h>
#include <hip/hip_bf16.h>

typedef __attribute__((ext_vector_type(8))) __bf16 bf16x8;
typedef __attribute__((ext_vector_type(4))) float f32x4;

#define F_DIM 512
#define D_DIM 128
#define RPB 128            // rows per bucket (bucket = row >> 7)
#define MAXBUK 1024
#define BIN_CHUNK 8192
#define CAPMAX 3072        // >= runtime cap (2813); LDS sizing

__device__ __forceinline__ unsigned short f32_to_bf16_rn(float x) {
    union { float f; unsigned u; } v; v.f = x;
    unsigned u = v.u;
    unsigned rounded = u + 0x7fffu + ((u >> 16) & 1u);
    return (unsigned short)(rounded >> 16);
}
__device__ __forceinline__ float bf16_to_f32(unsigned short u) {
    return __uint_as_float((unsigned)u << 16);
}

// Wt transpose-convert only (cursor is hipMemsetAsync'ed)
__global__ void prep_kernel(const float* __restrict__ W, unsigned short* __restrict__ Wt) {
    int idx = blockIdx.x * 256 + threadIdx.x;   // 65536 total
    int n = idx >> 9;
    int k = idx & 511;
    Wt[idx] = f32_to_bf16_rn(W[k * D_DIM + n]);
}

// FUSED co-scheduled kernel: blocks [0, binBlocks) run the edge-binning
// path; blocks [binBlocks, ...) run the R7 gemm path. The two halves touch
// disjoint data, so the CU scheduler overlaps bin's memory traffic with the
// gemm's latency bubbles (both are latency-bound individually).
__global__ __launch_bounds__(256) void fused_gemm_bin(
    const float* __restrict__ A, const unsigned short* __restrict__ Bt,
    unsigned short* __restrict__ Sb, int Nrows,
    const int* __restrict__ ei, const float* __restrict__ ev,
    int* __restrict__ cursor, uint2* __restrict__ ecv, int E, int nbuk,
    int cap, int binBlocks)
{
    __shared__ __align__(16) char smem[30720];
    const int tid = threadIdx.x;

    if ((int)blockIdx.x < binBlocks) {
        // ---------------- bin path (cursor starts zeroed) ----------------
        int* cnt = (int*)smem;
        int* bas = (int*)(smem + 4096);
        const int e0 = blockIdx.x * BIN_CHUNK;
        const int e1 = min(e0 + BIN_CHUNK, E);

        for (int i = tid; i < nbuk; i += 256) cnt[i] = 0;
        __syncthreads();
        for (int e = e0 + tid; e < e1; e += 256)
            atomicAdd(&cnt[ei[e] >> 7], 1);
        __syncthreads();
        for (int i = tid; i < nbuk; i += 256) {
            int c = cnt[i];
            bas[i] = c ? (i * cap + atomicAdd(&cursor[i], c)) : 0;
            cnt[i] = 0;
        }
        __syncthreads();
        for (int e = e0 + tid; e < e1; e += 256) {
            int r = ei[e];
            int b = r >> 7;
            int slot = atomicAdd(&cnt[b], 1);
            uint2 cv;
            cv.x = ((unsigned)ei[E + e] << 7) | (unsigned)(r & 127);
            cv.y = __float_as_uint(ev[e]);
            ecv[(size_t)bas[b] + slot] = cv;
        }
        return;
    }

    // ---------------- gemm path (R7 structure, verbatim) ----------------
    unsigned short* Al = (unsigned short*)smem;            // 2*64*40  = 10240 B
    unsigned short* Bl = (unsigned short*)(smem + 10240);  // 2*128*40 = 20480 B

    const int gb   = blockIdx.x - binBlocks;
    const int wave = tid >> 6;
    const int lane = tid & 63;
    const int g    = lane >> 4;
    const int r16  = lane & 15;
    const int m0   = gb * 64;

    const int sar = tid >> 2;
    const int skq = tid & 3;
    int arow = m0 + sar;
    if (arow >= Nrows) arow = Nrows - 1;
    const float* aptr = A + (size_t)arow * F_DIM + skq * 8;
    const int awoff = sar * 40 + skq * 8;

    const int sbr = tid >> 1;
    const int skh = tid & 1;
    const unsigned short* bptr = Bt + (size_t)sbr * F_DIM + skh * 16;
    const int bwoff = sbr * 40 + skh * 16;

    float4 ar0, ar1;
    uint4  br0, br1;

    auto loadAB = [&](int ks) {
        const float4* pa = (const float4*)(aptr + ks * 32);
        ar0 = pa[0]; ar1 = pa[1];
        const uint4* pb = (const uint4*)(bptr + ks * 32);
        br0 = pb[0]; br1 = pb[1];
    };
    auto storeAB = [&](int buf) {
        union { uint4 q; __bf16 h[8]; } u;
        u.h[0]=(__bf16)ar0.x; u.h[1]=(__bf16)ar0.y; u.h[2]=(__bf16)ar0.z; u.h[3]=(__bf16)ar0.w;
        u.h[4]=(__bf16)ar1.x; u.h[5]=(__bf16)ar1.y; u.h[6]=(__bf16)ar1.z; u.h[7]=(__bf16)ar1.w;
        *(uint4*)&Al[buf * 2560 + awoff] = u.q;
        unsigned short* bw = &Bl[buf * 5120 + bwoff];
        *(uint4*)bw       = br0;
        *(uint4*)(bw + 8) = br1;
    };

    f32x4 acc[8];
#pragma unroll
    for (int j = 0; j < 8; ++j) acc[j] = (f32x4)0.0f;

    loadAB(0);
    storeAB(0);
    __syncthreads();

#pragma unroll
    for (int ks = 0; ks < 16; ++ks) {
        const int cur = ks & 1;
        if (ks < 15) loadAB(ks + 1);

        const unsigned short* Ab = Al + cur * 2560;
        const unsigned short* Bb = Bl + cur * 5120;
        bf16x8 af = *(const bf16x8*)&Ab[(wave * 16 + r16) * 40 + g * 8];
#pragma unroll
        for (int nf = 0; nf < 8; ++nf) {
            bf16x8 bf = *(const bf16x8*)&Bb[(nf * 16 + r16) * 40 + g * 8];
            acc[nf] = __builtin_amdgcn_mfma_f32_16x16x32_bf16(af, bf, acc[nf], 0, 0, 0);
        }

        if (ks < 15) storeAB(cur ^ 1);
        __syncthreads();
    }

#pragma unroll
    for (int nf = 0; nf < 8; ++nf) {
#pragma unroll
        for (int r = 0; r < 4; ++r) {
            int row = m0 + wave * 16 + g * 4 + r;
            if (row < Nrows) {
                float v = acc[nf][r];
                Sb[(size_t)row * D_DIM + nf * 16 + r16] = f32_to_bf16_rn(v > 0.f ? v : 0.f);
            }
        }
    }
}

// FUSED sort+accumulate: one block per bucket, 512 threads, 8 waves.
// LDS counting-sort by local row, then each wave owns 16 rows processed in
// PAIRS over their merged (contiguous) sorted range: 8-deep unrolled gather
// loop with branchless mask-select into the two accumulator pairs
// (8 Sb-gathers in flight per lane). Fused identity+bias epilogue.
__global__ __launch_bounds__(512) void sortaccum_kernel(
    const uint2* __restrict__ ecv, const int* __restrict__ cursor,
    const unsigned short* __restrict__ Sb, const float* __restrict__ bias,
    float* __restrict__ out, int Nrows, int cap)
{
    __shared__ uint2 raw[CAPMAX];   // 24 KB
    __shared__ uint2 srt[CAPMAX];   // 24 KB
    __shared__ int cnt[RPB];
    __shared__ int base[RPB];
    __shared__ int scur[RPB];

    const int tid = threadIdx.x;
    const int b   = blockIdx.x;
    const int beg = b * cap;
    int n = cursor[b];                    // count (cursor started at 0)
    if (n > cap) n = cap;

    if (tid < RPB) cnt[tid] = 0;
    __syncthreads();
    for (int i = tid; i < n; i += 512) {
        uint2 cv = ecv[beg + i];
        raw[i] = cv;
        atomicAdd(&cnt[cv.x & 127], 1);
    }
    __syncthreads();
    if (tid < 64) {
        int carry = 0;
#pragma unroll
        for (int c = 0; c < 2; ++c) {
            int idx = c * 64 + tid;
            int v = cnt[idx];
            int orig = v;
            for (int d = 1; d < 64; d <<= 1) {
                int t = __shfl_up(v, d, 64);
                if (tid >= d) v += t;
            }
            int excl = carry + v - orig;
            base[idx] = excl;
            scur[idx] = excl;
            carry += __shfl(v, 63, 64);
        }
    }
    __syncthreads();
    for (int i = tid; i < n; i += 512) {
        uint2 cv = raw[i];
        int slot = atomicAdd(&scur[cv.x & 127], 1);
        srt[slot] = cv;
    }
    __syncthreads();

    const int wv   = tid >> 6;
    const int lane = tid & 63;
    const int c2   = lane * 2;
    const int r0g  = b * RPB;

#define GATHER(J) \
    uint2 cv##J = srt[i + J]; \
    ushort2 sv##J = *(const ushort2*)&Sb[(size_t)(cv##J.x >> 7) * D_DIM + c2];

#define ACCUM(J) { \
    float v = __uint_as_float(cv##J.y); \
    float sel = ((int)(cv##J.x & 127) == rl0) ? 1.f : 0.f; \
    float px = v * bf16_to_f32(sv##J.x); \
    float py = v * bf16_to_f32(sv##J.y); \
    ax0 += sel * px; ay0 += sel * py; \
    ax1 += px - sel * px; ay1 += py - sel * py; }

    for (int rr = 0; rr < 16; rr += 2) {
        const int rl0 = wv * 16 + rr;
        const int s  = base[rl0];
        const int e  = s + cnt[rl0] + cnt[rl0 + 1];

        float ax0 = 0.f, ay0 = 0.f, ax1 = 0.f, ay1 = 0.f;
        int i = s;
        for (; i + 7 < e; i += 8) {
            GATHER(0) GATHER(1) GATHER(2) GATHER(3)
            GATHER(4) GATHER(5) GATHER(6) GATHER(7)
            ACCUM(0) ACCUM(1) ACCUM(2) ACCUM(3)
            ACCUM(4) ACCUM(5) ACCUM(6) ACCUM(7)
        }
        for (; i < e; ++i) {
            GATHER(0)
            ACCUM(0)
        }

        int row0 = r0g + rl0;
        if (row0 < Nrows) {
            ushort2 so = *(const ushort2*)&Sb[(size_t)row0 * D_DIM + c2];
            float2 bv = *(const float2*)&bias[c2];
            float2 o;
            o.x = ax0 + bf16_to_f32(so.x) + bv.x;
            o.y = ay0 + bf16_to_f32(so.y) + bv.y;
            *(float2*)&out[(size_t)row0 * D_DIM + c2] = o;
        }
        int row1 = row0 + 1;
        if (row1 < Nrows) {
            ushort2 so = *(const ushort2*)&Sb[(size_t)row1 * D_DIM + c2];
            float2 bv = *(const float2*)&bias[c2];
            float2 o;
            o.x = ax1 + bf16_to_f32(so.x) + bv.x;
            o.y = ay1 + bf16_to_f32(so.y) + bv.y;
            *(float2*)&out[(size_t)row1 * D_DIM + c2] = o;
        }
    }
#undef GATHER
#undef ACCUM
}

extern "C" void kernel_launch(void* const* d_in, const int* in_sizes, int n_in,
                              void* d_out, int out_size, void* d_ws, size_t ws_size,
                              hipStream_t stream) {
    const float* feature = (const float*)d_in[0];
    const float* W       = (const float*)d_in[1];
    const float* bias    = (const float*)d_in[2];
    const float* ev      = (const float*)d_in[3];
    const int*   ei      = (const int*)d_in[4];
    float* out = (float*)d_out;

    const int N = in_sizes[0] / F_DIM;   // 100000
    const int E = in_sizes[3];           // 1600000
    const int nbuk = (N + RPB - 1) / RPB;            // 782
    int cap = (E + nbuk - 1) / nbuk;
    cap = cap + cap / 4 + 256;                       // ~2813 (<= CAPMAX)
    if (cap > CAPMAX) cap = CAPMAX;

    char* ws = (char*)d_ws;
    size_t cur = 0;
    auto alloc = [&](size_t bytes) -> void* {
        void* p = ws + cur;
        cur = (cur + bytes + 255) & ~(size_t)255;
        return p;
    };
    unsigned short* Sb     = (unsigned short*)alloc((size_t)N * D_DIM * 2);
    unsigned short* Wt     = (unsigned short*)alloc((size_t)D_DIM * F_DIM * 2);
    int*            cursor = (int*)alloc((size_t)nbuk * 4);
    uint2*          ecv    = (uint2*)alloc(((size_t)nbuk * cap + BIN_CHUNK) * 8);
    (void)ws_size;

    const int binBlocks  = (E + BIN_CHUNK - 1) / BIN_CHUNK;   // 196
    const int gemmBlocks = (N + 63) / 64;                     // 1563

    hipMemsetAsync(cursor, 0, (size_t)nbuk * 4, stream);
    prep_kernel<<<256, 256, 0, stream>>>(W, Wt);
    fused_gemm_bin<<<binBlocks + gemmBlocks, 256, 0, stream>>>(
        feature, Wt, Sb, N, ei, ev, cursor, ecv, E, nbuk, cap, binBlocks);
    sortaccum_kernel<<<nbuk, 512, 0, stream>>>(ecv, cursor, Sb, bias, out, N, cap);
}

// Round 12
// 198.657 us; speedup vs baseline: 1.2590x; 1.0016x over previous
//
#include <hip/hip_runtime.h>
#include <hip/hip_bf16.h>

typedef __attribute__((ext_vector_type(8))) __bf16 bf16x8;
typedef __attribute__((ext_vector_type(4))) float f32x4;

#define F_DIM 512
#define D_DIM 128
#define RPB 128            // rows per bucket (bucket = row >> 7)
#define MAXBUK 1024
#define BIN_CHUNK 8192
#define CAPMAX 3072        // >= runtime cap (2813); LDS sizing

__device__ __forceinline__ unsigned short f32_to_bf16_rn(float x) {
    union { float f; unsigned u; } v; v.f = x;
    unsigned u = v.u;
    unsigned rounded = u + 0x7fffu + ((u >> 16) & 1u);
    return (unsigned short)(rounded >> 16);
}
__device__ __forceinline__ float bf16_to_f32(unsigned short u) {
    return __uint_as_float((unsigned)u << 16);
}

// Wt transpose-convert only (cursor is hipMemsetAsync'ed)
__global__ void prep_kernel(const float* __restrict__ W, unsigned short* __restrict__ Wt) {
    int idx = blockIdx.x * 256 + threadIdx.x;   // 65536 total
    int n = idx >> 9;
    int k = idx & 511;
    Wt[idx] = f32_to_bf16_rn(W[k * D_DIM + n]);
}

// FUSED co-scheduled kernel: blocks [0, binBlocks) run the edge-binning
// path; blocks [binBlocks, ...) run the gemm path.
// GEMM: R7 64x128 tile, BK=32, but with a DEPTH-2 register pipeline
// (two named reg sets; loads for K(ks+3) issued at iter ks, consumed at
// iter ks+2 -> compiler emits counted vmcnt, never 0) and raw s_barrier
// (+ lgkmcnt(0)) instead of __syncthreads -> in-flight global loads are
// NOT drained at the barrier.
__global__ __launch_bounds__(256) void fused_gemm_bin(
    const float* __restrict__ A, const unsigned short* __restrict__ Bt,
    unsigned short* __restrict__ Sb, int Nrows,
    const int* __restrict__ ei, const float* __restrict__ ev,
    int* __restrict__ cursor, uint2* __restrict__ ecv, int E, int nbuk,
    int cap, int binBlocks)
{
    __shared__ __align__(16) char smem[30720];
    const int tid = threadIdx.x;

    if ((int)blockIdx.x < binBlocks) {
        // ---------------- bin path (cursor starts zeroed) ----------------
        int* cnt = (int*)smem;
        int* bas = (int*)(smem + 4096);
        const int e0 = blockIdx.x * BIN_CHUNK;
        const int e1 = min(e0 + BIN_CHUNK, E);

        for (int i = tid; i < nbuk; i += 256) cnt[i] = 0;
        __syncthreads();
        for (int e = e0 + tid; e < e1; e += 256)
            atomicAdd(&cnt[ei[e] >> 7], 1);
        __syncthreads();
        for (int i = tid; i < nbuk; i += 256) {
            int c = cnt[i];
            bas[i] = c ? (i * cap + atomicAdd(&cursor[i], c)) : 0;
            cnt[i] = 0;
        }
        __syncthreads();
        for (int e = e0 + tid; e < e1; e += 256) {
            int r = ei[e];
            int b = r >> 7;
            int slot = atomicAdd(&cnt[b], 1);
            uint2 cv;
            cv.x = ((unsigned)ei[E + e] << 7) | (unsigned)(r & 127);
            cv.y = __float_as_uint(ev[e]);
            ecv[(size_t)bas[b] + slot] = cv;
        }
        return;
    }

    // ---------------- gemm path ----------------
    unsigned short* Al = (unsigned short*)smem;            // 2*64*40  = 10240 B
    unsigned short* Bl = (unsigned short*)(smem + 10240);  // 2*128*40 = 20480 B

    const int gb   = blockIdx.x - binBlocks;
    const int wave = tid >> 6;
    const int lane = tid & 63;
    const int g    = lane >> 4;
    const int r16  = lane & 15;
    const int m0   = gb * 64;

    const int sar = tid >> 2;
    const int skq = tid & 3;
    int arow = m0 + sar;
    if (arow >= Nrows) arow = Nrows - 1;
    const float* aptr = A + (size_t)arow * F_DIM + skq * 8;
    const int awoff = sar * 40 + skq * 8;

    const int sbr = tid >> 1;
    const int skh = tid & 1;
    const unsigned short* bptr = Bt + (size_t)sbr * F_DIM + skh * 16;
    const int bwoff = sbr * 40 + skh * 16;

    // two named register sets (static, rule #20)
    float4 a0_0, a0_1; uint4 b0_0, b0_1;   // set 0
    float4 a1_0, a1_1; uint4 b1_0, b1_1;   // set 1

#define LOADSET(aR0, aR1, bR0, bR1, ks) { \
    const float4* pa = (const float4*)(aptr + (ks) * 32); \
    aR0 = pa[0]; aR1 = pa[1]; \
    const uint4* pb = (const uint4*)(bptr + (ks) * 32); \
    bR0 = pb[0]; bR1 = pb[1]; }

#define STORESET(aR0, aR1, bR0, bR1, buf) { \
    union { uint4 q; __bf16 h[8]; } u; \
    u.h[0]=(__bf16)aR0.x; u.h[1]=(__bf16)aR0.y; u.h[2]=(__bf16)aR0.z; u.h[3]=(__bf16)aR0.w; \
    u.h[4]=(__bf16)aR1.x; u.h[5]=(__bf16)aR1.y; u.h[6]=(__bf16)aR1.z; u.h[7]=(__bf16)aR1.w; \
    *(uint4*)&Al[(buf) * 2560 + awoff] = u.q; \
    unsigned short* bw = &Bl[(buf) * 5120 + bwoff]; \
    *(uint4*)bw       = bR0; \
    *(uint4*)(bw + 8) = bR1; }

    f32x4 acc[8];
#pragma unroll
    for (int j = 0; j < 8; ++j) acc[j] = (f32x4)0.0f;

    // prologue: K0 staged; K1 (set1) and K2 (set0) in flight
    LOADSET(a0_0, a0_1, b0_0, b0_1, 0);
    STORESET(a0_0, a0_1, b0_0, b0_1, 0);
    LOADSET(a1_0, a1_1, b1_0, b1_1, 1);
    LOADSET(a0_0, a0_1, b0_0, b0_1, 2);
    asm volatile("s_waitcnt lgkmcnt(0)" ::: "memory");
    __builtin_amdgcn_s_barrier();

#pragma unroll
    for (int ks = 0; ks < 16; ++ks) {
        const unsigned short* Ab = Al + (ks & 1) * 2560;
        const unsigned short* Bb = Bl + (ks & 1) * 5120;
        bf16x8 af = *(const bf16x8*)&Ab[(wave * 16 + r16) * 40 + g * 8];
#pragma unroll
        for (int nf = 0; nf < 8; ++nf) {
            bf16x8 bf = *(const bf16x8*)&Bb[(nf * 16 + r16) * 40 + g * 8];
            acc[nf] = __builtin_amdgcn_mfma_f32_16x16x32_bf16(af, bf, acc[nf], 0, 0, 0);
        }

        if (ks < 15) {
            if ((ks & 1) == 0) {
                // set1 holds K(ks+1): store it, then refill set1 with K(ks+3)
                STORESET(a1_0, a1_1, b1_0, b1_1, (ks + 1) & 1);
                if (ks + 3 < 16) LOADSET(a1_0, a1_1, b1_0, b1_1, ks + 3);
            } else {
                STORESET(a0_0, a0_1, b0_0, b0_1, (ks + 1) & 1);
                if (ks + 3 < 16) LOADSET(a0_0, a0_1, b0_0, b0_1, ks + 3);
            }
        }
        asm volatile("s_waitcnt lgkmcnt(0)" ::: "memory");
        __builtin_amdgcn_s_barrier();
    }
#undef LOADSET
#undef STORESET

#pragma unroll
    for (int nf = 0; nf < 8; ++nf) {
#pragma unroll
        for (int r = 0; r < 4; ++r) {
            int row = m0 + wave * 16 + g * 4 + r;
            if (row < Nrows) {
                float v = acc[nf][r];
                Sb[(size_t)row * D_DIM + nf * 16 + r16] = f32_to_bf16_rn(v > 0.f ? v : 0.f);
            }
        }
    }
}

// FUSED sort+accumulate: one block per bucket, 512 threads, 8 waves.
// LDS counting-sort by local row, then each wave owns 16 rows processed in
// PAIRS over their merged (contiguous) sorted range: 8-deep unrolled gather
// loop with branchless mask-select into the two accumulator pairs.
__global__ __launch_bounds__(512) void sortaccum_kernel(
    const uint2* __restrict__ ecv, const int* __restrict__ cursor,
    const unsigned short* __restrict__ Sb, const float* __restrict__ bias,
    float* __restrict__ out, int Nrows, int cap)
{
    __shared__ uint2 raw[CAPMAX];   // 24 KB
    __shared__ uint2 srt[CAPMAX];   // 24 KB
    __shared__ int cnt[RPB];
    __shared__ int base[RPB];
    __shared__ int scur[RPB];

    const int tid = threadIdx.x;
    const int b   = blockIdx.x;
    const int beg = b * cap;
    int n = cursor[b];                    // count (cursor started at 0)
    if (n > cap) n = cap;

    if (tid < RPB) cnt[tid] = 0;
    __syncthreads();
    for (int i = tid; i < n; i += 512) {
        uint2 cv = ecv[beg + i];
        raw[i] = cv;
        atomicAdd(&cnt[cv.x & 127], 1);
    }
    __syncthreads();
    if (tid < 64) {
        int carry = 0;
#pragma unroll
        for (int c = 0; c < 2; ++c) {
            int idx = c * 64 + tid;
            int v = cnt[idx];
            int orig = v;
            for (int d = 1; d < 64; d <<= 1) {
                int t = __shfl_up(v, d, 64);
                if (tid >= d) v += t;
            }
            int excl = carry + v - orig;
            base[idx] = excl;
            scur[idx] = excl;
            carry += __shfl(v, 63, 64);
        }
    }
    __syncthreads();
    for (int i = tid; i < n; i += 512) {
        uint2 cv = raw[i];
        int slot = atomicAdd(&scur[cv.x & 127], 1);
        srt[slot] = cv;
    }
    __syncthreads();

    const int wv   = tid >> 6;
    const int lane = tid & 63;
    const int c2   = lane * 2;
    const int r0g  = b * RPB;

#define GATHER(J) \
    uint2 cv##J = srt[i + J]; \
    ushort2 sv##J = *(const ushort2*)&Sb[(size_t)(cv##J.x >> 7) * D_DIM + c2];

#define ACCUM(J) { \
    float v = __uint_as_float(cv##J.y); \
    float sel = ((int)(cv##J.x & 127) == rl0) ? 1.f : 0.f; \
    float px = v * bf16_to_f32(sv##J.x); \
    float py = v * bf16_to_f32(sv##J.y); \
    ax0 += sel * px; ay0 += sel * py; \
    ax1 += px - sel * px; ay1 += py - sel * py; }

    for (int rr = 0; rr < 16; rr += 2) {
        const int rl0 = wv * 16 + rr;
        const int s  = base[rl0];
        const int e  = s + cnt[rl0] + cnt[rl0 + 1];

        float ax0 = 0.f, ay0 = 0.f, ax1 = 0.f, ay1 = 0.f;
        int i = s;
        for (; i + 7 < e; i += 8) {
            GATHER(0) GATHER(1) GATHER(2) GATHER(3)
            GATHER(4) GATHER(5) GATHER(6) GATHER(7)
            ACCUM(0) ACCUM(1) ACCUM(2) ACCUM(3)
            ACCUM(4) ACCUM(5) ACCUM(6) ACCUM(7)
        }
        for (; i < e; ++i) {
            GATHER(0)
            ACCUM(0)
        }

        int row0 = r0g + rl0;
        if (row0 < Nrows) {
            ushort2 so = *(const ushort2*)&Sb[(size_t)row0 * D_DIM + c2];
            float2 bv = *(const float2*)&bias[c2];
            float2 o;
            o.x = ax0 + bf16_to_f32(so.x) + bv.x;
            o.y = ay0 + bf16_to_f32(so.y) + bv.y;
            *(float2*)&out[(size_t)row0 * D_DIM + c2] = o;
        }
        int row1 = row0 + 1;
        if (row1 < Nrows) {
            ushort2 so = *(const ushort2*)&Sb[(size_t)row1 * D_DIM + c2];
            float2 bv = *(const float2*)&bias[c2];
            float2 o;
            o.x = ax1 + bf16_to_f32(so.x) + bv.x;
            o.y = ay1 + bf16_to_f32(so.y) + bv.y;
            *(float2*)&out[(size_t)row1 * D_DIM + c2] = o;
        }
    }
#undef GATHER
#undef ACCUM
}

extern "C" void kernel_launch(void* const* d_in, const int* in_sizes, int n_in,
                              void* d_out, int out_size, void* d_ws, size_t ws_size,
                              hipStream_t stream) {
    const float* feature = (const float*)d_in[0];
    const float* W       = (const float*)d_in[1];
    const float* bias    = (const float*)d_in[2];
    const float* ev      = (const float*)d_in[3];
    const int*   ei      = (const int*)d_in[4];
    float* out = (float*)d_out;

    const int N = in_sizes[0] / F_DIM;   // 100000
    const int E = in_sizes[3];           // 1600000
    const int nbuk = (N + RPB - 1) / RPB;            // 782
    int cap = (E + nbuk - 1) / nbuk;
    cap = cap + cap / 4 + 256;                       // ~2813 (<= CAPMAX)
    if (cap > CAPMAX) cap = CAPMAX;

    char* ws = (char*)d_ws;
    size_t cur = 0;
    auto alloc = [&](size_t bytes) -> void* {
        void* p = ws + cur;
        cur = (cur + bytes + 255) & ~(size_t)255;
        return p;
    };
    unsigned short* Sb     = (unsigned short*)alloc((size_t)N * D_DIM * 2);
    unsigned short* Wt     = (unsigned short*)alloc((size_t)D_DIM * F_DIM * 2);
    int*            cursor = (int*)alloc((size_t)nbuk * 4);
    uint2*          ecv    = (uint2*)alloc(((size_t)nbuk * cap + BIN_CHUNK) * 8);
    (void)ws_size;

    const int binBlocks  = (E + BIN_CHUNK - 1) / BIN_CHUNK;   // 196
    const int gemmBlocks = (N + 63) / 64;                     // 1563

    hipMemsetAsync(cursor, 0, (size_t)nbuk * 4, stream);
    prep_kernel<<<256, 256, 0, stream>>>(W, Wt);
    fused_gemm_bin<<<binBlocks + gemmBlocks, 256, 0, stream>>>(
        feature, Wt, Sb, N, ei, ev, cursor, ecv, E, nbuk, cap, binBlocks);
    sortaccum_kernel<<<nbuk, 512, 0, stream>>>(ecv, cursor, Sb, bias, out, N, cap);
}